// Round 1
// baseline (6040.580 us; speedup 1.0000x reference)
//
#include <hip/hip_runtime.h>
#include <math.h>
#include <stdint.h>

#define B 128
#define S 512
#define V 6000
#define E 100
#define H 256
#define G4 1024   /* 4*H */
#define T 9

/* workspace byte offsets (all 256-aligned) */
#define OFF_WT_F   0u
#define OFF_WT_B   (1u<<20)
#define OFF_PEMB_F (2u<<20)
#define PEMB_BYTES (V*G4*4u)              /* 24,576,000 */
#define OFF_PEMB_B (OFF_PEMB_F + PEMB_BYTES)
#define OFF_EMF    (OFF_PEMB_B + PEMB_BYTES)
#define EM_BYTES   (B*S*T*4u)             /* 2,359,296 */
#define OFF_EMB    (OFF_EMF + EM_BYTES)
#define OFF_BP     (OFF_EMB + EM_BYTES)
#define BP_BYTES   ((S-1)*B*16u)          /* 1,046,528 */
#define OFF_LT     (OFF_BP + BP_BYTES)
#define OFF_PT     (OFF_LT + 512u)

__device__ __forceinline__ float sigf(float x) { return 1.0f / (1.0f + expf(-x)); }

/* W_hh [4H][H] row-major  ->  wt[k*1024 + j*4 + q] = W_hh[q*256+j][k]
   so thread j reads a float4 (q=0..3 for unit j) per k, coalesced. */
__global__ __launch_bounds__(256) void k_transpose(const float* __restrict__ whf,
                                                   const float* __restrict__ whb,
                                                   char* __restrict__ ws) {
    int tid = blockIdx.x * 256 + threadIdx.x;      /* 0 .. 2*262144 */
    int d   = tid >> 18;
    int idx = tid & 262143;
    int q = idx & 3, j = (idx >> 2) & 255, k = idx >> 10;
    const float* w  = d ? whb : whf;
    float* wt = (float*)(ws + (d ? OFF_WT_B : OFF_WT_F));
    wt[idx] = w[(q * H + j) * H + k];
}

/* pemb[v][g] = bias[g] + sum_e emb[v][e] * W_ih[g][e],  g = q*256 + j */
__global__ __launch_bounds__(256) void k_pemb(const float* __restrict__ emb,
                                              const float* __restrict__ wf, const float* __restrict__ bf,
                                              const float* __restrict__ wb, const float* __restrict__ bb,
                                              char* __restrict__ ws) {
    int blk = blockIdx.x;                   /* 0..749 */
    int d   = blk >= 375;
    int vb  = d ? blk - 375 : blk;
    const float* W    = d ? wb : wf;
    const float* bias = d ? bb : bf;
    float* pe = (float*)(ws + (d ? OFF_PEMB_B : OFF_PEMB_F));

    __shared__ float es[16 * E];
    for (int i = threadIdx.x; i < 16 * E; i += 256) es[i] = emb[vb * 16 * E + i];
    __syncthreads();

    int j = threadIdx.x;
    float acc[4][16];
    #pragma unroll
    for (int q = 0; q < 4; q++) {
        float bq = bias[q * H + j];
        #pragma unroll
        for (int v = 0; v < 16; v++) acc[q][v] = bq;
    }
    for (int e = 0; e < E; e++) {
        float w0 = W[(0 * H + j) * E + e];
        float w1 = W[(1 * H + j) * E + e];
        float w2 = W[(2 * H + j) * E + e];
        float w3 = W[(3 * H + j) * E + e];
        #pragma unroll
        for (int v = 0; v < 16; v++) {
            float x = es[v * E + e];
            acc[0][v] += w0 * x; acc[1][v] += w1 * x;
            acc[2][v] += w2 * x; acc[3][v] += w3 * x;
        }
    }
    for (int v = 0; v < 16; v++)
        #pragma unroll
        for (int q = 0; q < 4; q++)
            pe[(vb * 16 + v) * G4 + q * H + j] = acc[q][v];
}

/* One block per (dir, batch). Thread j owns hidden unit j; h broadcast in LDS;
   W_hh streamed from L2 (1 MB/step); emissions fused (per-dir buffer). */
__global__ __launch_bounds__(256) void k_lstm(const int* __restrict__ data,
                                              const float* __restrict__ mlpW,
                                              const float* __restrict__ mlpb,
                                              char* __restrict__ ws) {
    int blk = blockIdx.x;
    int b = blk & 127, d = blk >> 7;
    const float4* wt4 = (const float4*)(ws + (d ? OFF_WT_B : OFF_WT_F));
    const float*  pe  = (const float*)(ws + (d ? OFF_PEMB_B : OFF_PEMB_F));
    float* em = (float*)(ws + (d ? OFF_EMB : OFF_EMF));

    __shared__ float hs[H];
    __shared__ float mw[T * H];
    __shared__ float red[T * 4];

    int j = threadIdx.x, lane = j & 63, wid = j >> 6;
    for (int i = j; i < T * H; i += 256) {
        int t = i >> 8, k = i & 255;
        mw[i] = mlpW[t * (2 * H) + d * H + k];
    }
    hs[j] = 0.0f;
    float c = 0.0f;
    __syncthreads();

    for (int ss = 0; ss < S; ss++) {
        int sp  = d ? (S - 1 - ss) : ss;
        int tok = data[b * S + sp];
        const float* per = pe + (size_t)tok * G4;
        float a0 = per[j], a1 = per[H + j], a2 = per[2 * H + j], a3 = per[3 * H + j];

        const float4* wrow = wt4 + j;
        #pragma unroll 8
        for (int k = 0; k < H; k++) {
            float4 w = wrow[k * H];        /* floats: k*1024 + j*4 + {0..3} */
            float hk = hs[k];
            a0 += w.x * hk; a1 += w.y * hk; a2 += w.z * hk; a3 += w.w * hk;
        }

        float ig = sigf(a0), fg = sigf(a1), gg = tanhf(a2), og = sigf(a3);
        c = fg * c + ig * gg;
        float hn = og * tanhf(c);

        __syncthreads();
        hs[j] = hn;
        __syncthreads();

        #pragma unroll
        for (int t = 0; t < T; t++) {
            float v = hn * mw[t * H + j];
            v += __shfl_down(v, 32, 64); v += __shfl_down(v, 16, 64);
            v += __shfl_down(v, 8, 64);  v += __shfl_down(v, 4, 64);
            v += __shfl_down(v, 2, 64);  v += __shfl_down(v, 1, 64);
            if (lane == 0) red[t * 4 + wid] = v;
        }
        __syncthreads();
        if (j < T) {
            float sum = red[j * 4] + red[j * 4 + 1] + red[j * 4 + 2] + red[j * 4 + 3];
            if (!d) sum += mlpb[j];
            em[(b * S + sp) * T + j] = sum;
        }
        /* next iteration's sync pair protects red/hs reuse */
    }
}

/* Viterbi forward: one wave per batch, lane t = tag. Strict-> ascending scan
   matches jnp.argmax first-index tie-breaking. */
__global__ __launch_bounds__(64) void k_vit(const int* __restrict__ data,
                                            const float* __restrict__ strans,
                                            const float* __restrict__ trans,
                                            const float* __restrict__ etrans,
                                            float* __restrict__ out,
                                            char* __restrict__ ws) {
    int b = blockIdx.x, t = threadIdx.x;
    const float* emf = (const float*)(ws + OFF_EMF);
    const float* emb = (const float*)(ws + OFF_EMB);
    char* bp = ws + OFF_BP;
    int*  lt = (int*)(ws + OFF_LT);
    bool act = t < T;

    float trp[T];
    if (act) {
        #pragma unroll
        for (int p = 0; p < T; p++) trp[p] = trans[p * T + t];
    }
    float score = -1e30f;
    if (act) score = strans[t] + emf[(b * S) * T + t] + emb[(b * S) * T + t];

    for (int s = 1; s < S; s++) {
        float e = 0.0f;
        if (act) e = emf[(b * S + s) * T + t] + emb[(b * S + s) * T + t];
        float best = __shfl(score, 0, 64) + trp[0];
        int bpi = 0;
        #pragma unroll
        for (int p = 1; p < T; p++) {
            float cand = __shfl(score, p, 64) + trp[p];
            if (cand > best) { best = cand; bpi = p; }
        }
        int m = data[b * S + s] != 0;
        if (act) {
            score = m ? (best + e) : score;
            bp[((size_t)(s - 1) * B + b) * 16 + t] = (char)bpi;
        }
    }
    float fin = act ? score + etrans[t] : -1e30f;
    float bv = __shfl(fin, 0, 64);
    int bi = 0;
    #pragma unroll
    for (int p = 1; p < T; p++) {
        float v = __shfl(fin, p, 64);
        if (v > bv) { bv = v; bi = p; }
    }
    if (t == 0) { out[B * S + b] = bv; lt[b] = bi; }
}

/* Backtrack: thread = batch; bp row address is tag-independent -> pipelined loads */
__global__ __launch_bounds__(128) void k_back(const int* __restrict__ data, char* __restrict__ ws) {
    int b = threadIdx.x;
    const int4* bp4 = (const int4*)(ws + OFF_BP);
    const int*  lt  = (const int*)(ws + OFF_LT);
    int* pt = (int*)(ws + OFF_PT);
    int tag = lt[b];
    pt[(S - 1) * B + b] = tag;
    for (int p = S - 2; p >= 0; p--) {
        int4 r = bp4[(size_t)p * B + b];
        int m = data[b * S + p + 1] != 0;
        unsigned w = (unsigned)(tag < 8 ? (tag < 4 ? r.x : r.y) : r.z);
        int nt = (int)((w >> ((tag & 3) * 8)) & 0xff);
        tag = m ? nt : tag;
        pt[p * B + b] = tag;
    }
}

/* paths -> float output with mask zeroing */
__global__ __launch_bounds__(256) void k_fin(const int* __restrict__ data,
                                             float* __restrict__ out,
                                             const char* __restrict__ ws) {
    int tid = blockIdx.x * 256 + threadIdx.x;   /* 65536 */
    const int* pt = (const int*)(ws + OFF_PT);
    int b = tid >> 9, p = tid & 511;
    out[tid] = (data[tid] != 0) ? (float)pt[p * B + b] : 0.0f;
}

extern "C" void kernel_launch(void* const* d_in, const int* in_sizes, int n_in,
                              void* d_out, int out_size, void* d_ws, size_t ws_size,
                              hipStream_t stream) {
    const int*   data = (const int*)d_in[0];
    /* d_in[1] = mask (bool) — unused; mask == (data != 0) */
    const float* emb  = (const float*)d_in[2];
    const float* wihf = (const float*)d_in[3];
    const float* whhf = (const float*)d_in[4];
    const float* bf   = (const float*)d_in[5];
    const float* wihb = (const float*)d_in[6];
    const float* whhb = (const float*)d_in[7];
    const float* bb   = (const float*)d_in[8];
    const float* mlpW = (const float*)d_in[9];
    const float* mlpb = (const float*)d_in[10];
    const float* st   = (const float*)d_in[11];
    const float* tr   = (const float*)d_in[12];
    const float* et   = (const float*)d_in[13];
    float* out = (float*)d_out;
    char*  ws  = (char*)d_ws;

    hipLaunchKernelGGL(k_transpose, dim3(2048), dim3(256), 0, stream, whhf, whhb, ws);
    hipLaunchKernelGGL(k_pemb,      dim3(750),  dim3(256), 0, stream, emb, wihf, bf, wihb, bb, ws);
    hipLaunchKernelGGL(k_lstm,      dim3(256),  dim3(256), 0, stream, data, mlpW, mlpb, ws);
    hipLaunchKernelGGL(k_vit,       dim3(128),  dim3(64),  0, stream, data, st, tr, et, out, ws);
    hipLaunchKernelGGL(k_back,      dim3(1),    dim3(128), 0, stream, data, ws);
    hipLaunchKernelGGL(k_fin,       dim3(256),  dim3(256), 0, stream, data, out, ws);
}

// Round 2
// 5867.279 us; speedup vs baseline: 1.0295x; 1.0295x over previous
//
#include <hip/hip_runtime.h>
#include <math.h>
#include <stdint.h>

#define B 128
#define S 512
#define V 6000
#define E 100
#define H 256
#define G4 1024   /* 4*H */
#define T 9

/* workspace byte offsets (all 256-aligned) */
#define OFF_WT_F   0u
#define OFF_WT_B   (1u<<20)
#define OFF_PEMB_F (2u<<20)
#define PEMB_BYTES (V*G4*4u)              /* 24,576,000 */
#define OFF_PEMB_B (OFF_PEMB_F + PEMB_BYTES)
#define OFF_EMF    (OFF_PEMB_B + PEMB_BYTES)
#define EM_BYTES   (B*S*T*4u)             /* 2,359,296 */
#define OFF_EMB    (OFF_EMF + EM_BYTES)
#define OFF_BP     (OFF_EMB + EM_BYTES)
#define BP_BYTES   ((S-1)*B*16u)          /* 1,046,528 */
#define OFF_LT     (OFF_BP + BP_BYTES)
#define OFF_PT     (OFF_LT + 512u)

__device__ __forceinline__ float sigf(float x) { return 1.0f / (1.0f + expf(-x)); }

/* packed-pair fma: hoping SLP forms v_pk_fma_f32 (scalar w broadcast to both halves) */
__device__ __forceinline__ float2 pkfma(float s, float2 h, float2 a) {
    return make_float2(fmaf(s, h.x, a.x), fmaf(s, h.y, a.y));
}

/* W_hh [4H][H] row-major  ->  wt[k*1024 + j*4 + q] = W_hh[q*256+j][k]
   so thread j reads a float4 (q=0..3 for unit j) per k, coalesced. */
__global__ __launch_bounds__(256) void k_transpose(const float* __restrict__ whf,
                                                   const float* __restrict__ whb,
                                                   char* __restrict__ ws) {
    int tid = blockIdx.x * 256 + threadIdx.x;      /* 0 .. 2*262144 */
    int d   = tid >> 18;
    int idx = tid & 262143;
    int q = idx & 3, j = (idx >> 2) & 255, k = idx >> 10;
    const float* w  = d ? whb : whf;
    float* wt = (float*)(ws + (d ? OFF_WT_B : OFF_WT_F));
    wt[idx] = w[(q * H + j) * H + k];
}

/* pemb[v][g] = bias[g] + sum_e emb[v][e] * W_ih[g][e],  g = q*256 + j */
__global__ __launch_bounds__(256) void k_pemb(const float* __restrict__ emb,
                                              const float* __restrict__ wf, const float* __restrict__ bf,
                                              const float* __restrict__ wb, const float* __restrict__ bb,
                                              char* __restrict__ ws) {
    int blk = blockIdx.x;                   /* 0..749 */
    int d   = blk >= 375;
    int vb  = d ? blk - 375 : blk;
    const float* W    = d ? wb : wf;
    const float* bias = d ? bb : bf;
    float* pe = (float*)(ws + (d ? OFF_PEMB_B : OFF_PEMB_F));

    __shared__ float es[16 * E];
    for (int i = threadIdx.x; i < 16 * E; i += 256) es[i] = emb[vb * 16 * E + i];
    __syncthreads();

    int j = threadIdx.x;
    float acc[4][16];
    #pragma unroll
    for (int q = 0; q < 4; q++) {
        float bq = bias[q * H + j];
        #pragma unroll
        for (int v = 0; v < 16; v++) acc[q][v] = bq;
    }
    for (int e = 0; e < E; e++) {
        float w0 = W[(0 * H + j) * E + e];
        float w1 = W[(1 * H + j) * E + e];
        float w2 = W[(2 * H + j) * E + e];
        float w3 = W[(3 * H + j) * E + e];
        #pragma unroll
        for (int v = 0; v < 16; v++) {
            float x = es[v * E + e];
            acc[0][v] += w0 * x; acc[1][v] += w1 * x;
            acc[2][v] += w2 * x; acc[3][v] += w3 * x;
        }
    }
    for (int v = 0; v < 16; v++)
        #pragma unroll
        for (int q = 0; q < 4; q++)
            pe[(vb * 16 + v) * G4 + q * H + j] = acc[q][v];
}

/* One block per (dir, batch-pair). 512 threads: j = tid&255 (hidden unit),
   ks = tid>>8 (k-half). Each block streams W once per step for 2 batches
   (halves L2 traffic vs NB=1). Partial gates exchanged via LDS. */
__global__ __launch_bounds__(512) void k_lstm(const int* __restrict__ data,
                                              const float* __restrict__ mlpW,
                                              const float* __restrict__ mlpb,
                                              char* __restrict__ ws) {
    int blk = blockIdx.x;              /* 128 blocks: dir = blk>>6, bg = blk&63 */
    int d = blk >> 6, bg = blk & 63;
    int b0 = bg << 1;
    const float4* wt4 = (const float4*)(ws + (d ? OFF_WT_B : OFF_WT_F));
    const float*  pe  = (const float*)(ws + (d ? OFF_PEMB_B : OFF_PEMB_F));
    float* em = (float*)(ws + (d ? OFF_EMB : OFF_EMF));

    __shared__ float2 hs2[H];          /* (batch0, batch1) h per unit */
    __shared__ float part[8][H];       /* k-half-1 partials: [nb*4+q][j] */
    __shared__ float mw[T * H];
    __shared__ float red[2][T][4];

    int tid = threadIdx.x;
    int j = tid & 255, ks = tid >> 8;
    int lane = tid & 63, w4 = (tid >> 6) & 3;

    for (int i = tid; i < T * H; i += 512) {
        int t = i >> 8, k = i & 255;
        mw[i] = mlpW[t * (2 * H) + d * H + k];
    }
    if (ks == 0) hs2[j] = make_float2(0.f, 0.f);
    float c0 = 0.f, c1 = 0.f;
    __syncthreads();

    for (int ss = 0; ss < S; ss++) {
        int sp  = d ? (S - 1 - ss) : ss;
        int tok = data[(b0 + ks) * S + sp];
        const float* per = pe + (size_t)tok * G4;
        float p0 = per[j], p1 = per[H + j], p2 = per[2 * H + j], p3 = per[3 * H + j];
        /* acc.x = batch0, acc.y = batch1; pemb added once (by the matching ks) */
        float2 a0, a1, a2, a3;
        if (ks == 0) {
            a0 = make_float2(p0, 0.f); a1 = make_float2(p1, 0.f);
            a2 = make_float2(p2, 0.f); a3 = make_float2(p3, 0.f);
        } else {
            a0 = make_float2(0.f, p0); a1 = make_float2(0.f, p1);
            a2 = make_float2(0.f, p2); a3 = make_float2(0.f, p3);
        }
        const float4* wrow  = wt4 + (ks << 15) + j;   /* float4 idx: k*256 + j */
        const float2* hbase = hs2 + (ks << 7);
        #pragma unroll 8
        for (int kk = 0; kk < 128; kk++) {
            float4 w = wrow[kk << 8];
            float2 h = hbase[kk];
            a0 = pkfma(w.x, h, a0);
            a1 = pkfma(w.y, h, a1);
            a2 = pkfma(w.z, h, a2);
            a3 = pkfma(w.w, h, a3);
        }
        if (ks == 1) {
            part[0][j] = a0.x; part[1][j] = a1.x; part[2][j] = a2.x; part[3][j] = a3.x;
            part[4][j] = a0.y; part[5][j] = a1.y; part[6][j] = a2.y; part[7][j] = a3.y;
        }
        __syncthreads();
        if (ks == 0) {
            float i0 = sigf(a0.x + part[0][j]);
            float f0 = sigf(a1.x + part[1][j]);
            float g0 = tanhf(a2.x + part[2][j]);
            float o0 = sigf(a3.x + part[3][j]);
            c0 = f0 * c0 + i0 * g0;
            float h0 = o0 * tanhf(c0);
            float i1 = sigf(a0.y + part[4][j]);
            float f1 = sigf(a1.y + part[5][j]);
            float g1 = tanhf(a2.y + part[6][j]);
            float o1 = sigf(a3.y + part[7][j]);
            c1 = f1 * c1 + i1 * g1;
            float h1 = o1 * tanhf(c1);
            hs2[j] = make_float2(h0, h1);
        }
        __syncthreads();
        float2 hv = hs2[j];
        float hn = ks ? hv.y : hv.x;
        #pragma unroll
        for (int t = 0; t < T; t++) {
            float v = hn * mw[t * H + j];
            v += __shfl_down(v, 32, 64); v += __shfl_down(v, 16, 64);
            v += __shfl_down(v, 8, 64);  v += __shfl_down(v, 4, 64);
            v += __shfl_down(v, 2, 64);  v += __shfl_down(v, 1, 64);
            if (lane == 0) red[ks][t][w4] = v;
        }
        __syncthreads();
        if (tid < 2 * T) {
            int nb = tid >= T, t = tid - nb * T;
            float sum = red[nb][t][0] + red[nb][t][1] + red[nb][t][2] + red[nb][t][3];
            if (!d) sum += mlpb[t];
            em[((size_t)(b0 + nb) * S + sp) * T + t] = sum;
        }
    }
}

/* Viterbi forward: one wave per batch, lane t = tag. Strict-> ascending scan
   matches jnp.argmax first-index tie-breaking. */
__global__ __launch_bounds__(64) void k_vit(const int* __restrict__ data,
                                            const float* __restrict__ strans,
                                            const float* __restrict__ trans,
                                            const float* __restrict__ etrans,
                                            float* __restrict__ out,
                                            char* __restrict__ ws) {
    int b = blockIdx.x, t = threadIdx.x;
    const float* emf = (const float*)(ws + OFF_EMF);
    const float* emb = (const float*)(ws + OFF_EMB);
    char* bp = ws + OFF_BP;
    int*  lt = (int*)(ws + OFF_LT);
    bool act = t < T;

    float trp[T];
    if (act) {
        #pragma unroll
        for (int p = 0; p < T; p++) trp[p] = trans[p * T + t];
    }
    float score = -1e30f;
    if (act) score = strans[t] + emf[(b * S) * T + t] + emb[(b * S) * T + t];

    for (int s = 1; s < S; s++) {
        float e = 0.0f;
        if (act) e = emf[(b * S + s) * T + t] + emb[(b * S + s) * T + t];
        float best = __shfl(score, 0, 64) + trp[0];
        int bpi = 0;
        #pragma unroll
        for (int p = 1; p < T; p++) {
            float cand = __shfl(score, p, 64) + trp[p];
            if (cand > best) { best = cand; bpi = p; }
        }
        int m = data[b * S + s] != 0;
        if (act) {
            score = m ? (best + e) : score;
            bp[((size_t)(s - 1) * B + b) * 16 + t] = (char)bpi;
        }
    }
    float fin = act ? score + etrans[t] : -1e30f;
    float bv = __shfl(fin, 0, 64);
    int bi = 0;
    #pragma unroll
    for (int p = 1; p < T; p++) {
        float v = __shfl(fin, p, 64);
        if (v > bv) { bv = v; bi = p; }
    }
    if (t == 0) { out[B * S + b] = bv; lt[b] = bi; }
}

/* Backtrack: thread = batch; bp row address is tag-independent -> pipelined loads */
__global__ __launch_bounds__(128) void k_back(const int* __restrict__ data, char* __restrict__ ws) {
    int b = threadIdx.x;
    const int4* bp4 = (const int4*)(ws + OFF_BP);
    const int*  lt  = (const int*)(ws + OFF_LT);
    int* pt = (int*)(ws + OFF_PT);
    int tag = lt[b];
    pt[(S - 1) * B + b] = tag;
    for (int p = S - 2; p >= 0; p--) {
        int4 r = bp4[(size_t)p * B + b];
        int m = data[b * S + p + 1] != 0;
        unsigned w = (unsigned)(tag < 8 ? (tag < 4 ? r.x : r.y) : r.z);
        int nt = (int)((w >> ((tag & 3) * 8)) & 0xff);
        tag = m ? nt : tag;
        pt[p * B + b] = tag;
    }
}

/* paths -> float output with mask zeroing */
__global__ __launch_bounds__(256) void k_fin(const int* __restrict__ data,
                                             float* __restrict__ out,
                                             const char* __restrict__ ws) {
    int tid = blockIdx.x * 256 + threadIdx.x;   /* 65536 */
    const int* pt = (const int*)(ws + OFF_PT);
    int b = tid >> 9, p = tid & 511;
    out[tid] = (data[tid] != 0) ? (float)pt[p * B + b] : 0.0f;
}

extern "C" void kernel_launch(void* const* d_in, const int* in_sizes, int n_in,
                              void* d_out, int out_size, void* d_ws, size_t ws_size,
                              hipStream_t stream) {
    const int*   data = (const int*)d_in[0];
    /* d_in[1] = mask (bool) — unused; mask == (data != 0) */
    const float* emb  = (const float*)d_in[2];
    const float* wihf = (const float*)d_in[3];
    const float* whhf = (const float*)d_in[4];
    const float* bf   = (const float*)d_in[5];
    const float* wihb = (const float*)d_in[6];
    const float* whhb = (const float*)d_in[7];
    const float* bb   = (const float*)d_in[8];
    const float* mlpW = (const float*)d_in[9];
    const float* mlpb = (const float*)d_in[10];
    const float* st   = (const float*)d_in[11];
    const float* tr   = (const float*)d_in[12];
    const float* et   = (const float*)d_in[13];
    float* out = (float*)d_out;
    char*  ws  = (char*)d_ws;

    hipLaunchKernelGGL(k_transpose, dim3(2048), dim3(256), 0, stream, whhf, whhb, ws);
    hipLaunchKernelGGL(k_pemb,      dim3(750),  dim3(256), 0, stream, emb, wihf, bf, wihb, bb, ws);
    hipLaunchKernelGGL(k_lstm,      dim3(128),  dim3(512), 0, stream, data, mlpW, mlpb, ws);
    hipLaunchKernelGGL(k_vit,       dim3(128),  dim3(64),  0, stream, data, st, tr, et, out, ws);
    hipLaunchKernelGGL(k_back,      dim3(1),    dim3(128), 0, stream, data, ws);
    hipLaunchKernelGGL(k_fin,       dim3(256),  dim3(256), 0, stream, data, out, ws);
}